// Round 4
// baseline (633.935 us; speedup 1.0000x reference)
//
#include <hip/hip_runtime.h>

#define NSMP 8192
#define INW  8712   // input row stride (floats)
#define OUTW 8448   // output row stride (floats)
#define AOFF 512    // column offset of A block inside input
#define DO   256    // DOUT

typedef __attribute__((ext_vector_type(4)))  float f32x4;
typedef __attribute__((ext_vector_type(8)))  short short8;
typedef __attribute__((ext_vector_type(16))) float floatx16;

typedef __attribute__((address_space(1))) const unsigned int* gptr_t;
typedef __attribute__((address_space(3)))       unsigned int* lptr_t;

// pack two fp32 -> two bf16 (truncation; numerics identical to prior passing versions)
__device__ __forceinline__ unsigned pk_bf16(float lo, float hi) {
    return (__float_as_uint(lo) >> 16) | (__float_as_uint(hi) & 0xffff0000u);
}

// async global->LDS, 16B per lane; LDS dest = wave-uniform base + lane*16
__device__ __forceinline__ void gload_lds16(const void* g, void* l) {
    __builtin_amdgcn_global_load_lds((gptr_t)g, (lptr_t)l, 16, 0, 0);
}

// ------ Kernel A: copy A+I to out[:,256:], col sums -> d, bf16 A -> aP ---------
__global__ __launch_bounds__(256) void kcopy(const float* __restrict__ in,
                                             float* __restrict__ out,
                                             float* __restrict__ d,
                                             unsigned short* __restrict__ aP) {
    const int t  = threadIdx.x;
    const int j0 = blockIdx.x * 1024;   // 8 col tiles of 1024
    const int i0 = blockIdx.y * 32;     // 256 row tiles of 32
    const int jc = j0 + 4 * t;
    const float*    src = in  + (size_t)i0 * INW  + AOFF + jc;
    float*          dst = out + (size_t)i0 * OUTW + DO   + jc;
    unsigned short* ap  = aP  + (size_t)i0 * NSMP + jc;
    f32x4 cs = {0.f, 0.f, 0.f, 0.f};
#pragma unroll 8
    for (int r = 0; r < 32; ++r) {
        f32x4 v = __builtin_nontemporal_load((const f32x4*)(src + (size_t)r * INW));
        uint2 pb;                                     // raw A (no +I) in bf16 for kmm
        pb.x = pk_bf16(v[0], v[1]);
        pb.y = pk_bf16(v[2], v[3]);
        *(uint2*)(ap + (size_t)r * NSMP) = pb;
        int di = (i0 + r) - j0;                       // diagonal col within tile
        if ((di >> 2) == t) {
            int s = di & 3;
            v[0] += (s == 0); v[1] += (s == 1); v[2] += (s == 2); v[3] += (s == 3);
        }
        cs += v;
        __builtin_nontemporal_store(v, (f32x4*)(dst + (size_t)r * OUTW));
    }
    atomicAdd(&d[jc + 0], cs[0]);
    atomicAdd(&d[jc + 1], cs[1]);
    atomicAdd(&d[jc + 2], cs[2]);
    atomicAdd(&d[jc + 3], cs[3]);
}

// ------- Kernel B: support = X@W, write s' packed k-major: sP[oct=k/8][col][k%8] ----
__global__ __launch_bounds__(256) void ksupport(const float* __restrict__ in,
                                                const float* __restrict__ w,
                                                const float* __restrict__ d,
                                                float* __restrict__ dinv,
                                                unsigned short* __restrict__ sP) {
    const int c  = threadIdx.x;          // output column 0..255
    const int r0 = blockIdx.x * 8;       // 8 support-rows per block = one k-octet
    const float* X = in + (size_t)r0 * INW;   // X = input[:, :512]
    float acc[8] = {0.f, 0.f, 0.f, 0.f, 0.f, 0.f, 0.f, 0.f};
#pragma unroll 4
    for (int k = 0; k < 512; ++k) {
        float wv = w[(size_t)k * DO + c];
#pragma unroll
        for (int r = 0; r < 8; ++r)
            acc[r] = fmaf(X[(size_t)r * INW + k], wv, acc[r]);  // X load wave-uniform -> s_load
    }
    union { unsigned short h[8]; uint4 u; } pk;
#pragma unroll
    for (int r = 0; r < 8; ++r) {
        float dv = rsqrtf(d[r0 + r]);
        unsigned ub = __float_as_uint(acc[r] * dv);
        ub += 0x7fffu + ((ub >> 16) & 1u);            // RNE to bf16
        pk.h[r] = (unsigned short)(ub >> 16);
    }
    *(uint4*)(sP + (size_t)(r0 >> 3) * (DO * 8) + (size_t)c * 8) = pk.u;
    if (c < 8) dinv[r0 + c] = rsqrtf(d[r0 + c]);
}

// ---------------- Kernel C: out[:, :256] = dinv_i * (A0 @ s' + s'_i) -----------
// Counted-vmcnt 3-deep pipeline (T4): all loop VMEM = gload_lds, 5 issues/wave/step.
// Per step: wait vmcnt(5) [2-step-old loads] -> barrier -> issue step s+2 -> MFMA s.
// Race-free: wait BEFORE barrier => after barrier ALL waves' step-s LDS writes done.
// A: 3x4KB bf16 XOR-swizzled-source tiles; B: 3x16KB [oct][col][8] tiles. 60KB LDS.
__global__ __launch_bounds__(256, 2) void kmm(const unsigned short* __restrict__ aP,
                                              const unsigned short* __restrict__ sP,
                                              const float* __restrict__ dinv,
                                              float* __restrict__ out) {
    __shared__ __align__(16) unsigned short lA[3][32 * 64];      // 12 KB
    __shared__ __align__(16) unsigned short lB[3][8 * 128 * 8];  // 48 KB

    const int b  = blockIdx.x;
    // XCD-pair swizzle: blocks b and b+8 (same rg, ch=0/1) land on the same XCD (b%8)
    const int rg = ((b >> 4) << 3) + (b & 7);   // 0..255 row group
    const int ch = (b >> 3) & 1;                // column half
    const int tid = threadIdx.x;
    const int w = tid >> 6, lane = tid & 63;
    const int m = lane & 31, q = lane >> 5;
    const int i0 = rg * 32;
    const int cc = ch * 128 + w * 32 + m;

    // A stage: wave w stages rows w*8..w*8+7; lane -> (row = l>>3, slot = l&7);
    // global source pre-swizzled (slot g holds granule g^(row&7)) -> swizzled ds_read
    const int srow = lane >> 3;
    const int sg   = lane & 7;
    const unsigned short* aSrc = aP + (size_t)(i0 + w * 8 + srow) * NSMP
                                    + 8 * (sg ^ (srow & 7));
    // B stage: wave w stages octs {w, w+4}, two 64-col halves each (1KB contiguous)
    const unsigned short* bSrc = sP + (size_t)(ch * 128 + lane) * 8;

    floatx16 acc;
#pragma unroll
    for (int z = 0; z < 16; ++z) acc[z] = 0.f;

    // 5 gload_lds per wave per step, always (fixed vmcnt bookkeeping)
#define STAGE(buf, t) do {                                                     \
        const int O0_ = (t) * 8 + w;                                           \
        gload_lds16(aSrc + (size_t)(t) * 64,            &lA[buf][w * 512]);    \
        gload_lds16(bSrc + (size_t)O0_ * 2048,          &lB[buf][w * 1024]);   \
        gload_lds16(bSrc + (size_t)O0_ * 2048 + 512,    &lB[buf][w * 1024 + 512]); \
        gload_lds16(bSrc + (size_t)(O0_ + 4) * 2048,       &lB[buf][(w + 4) * 1024]); \
        gload_lds16(bSrc + (size_t)(O0_ + 4) * 2048 + 512, &lB[buf][(w + 4) * 1024 + 512]); \
    } while (0)

#define COMPUTE(buf) do {                                                      \
        const unsigned short* lAc_ = &lA[buf][0];                              \
        const unsigned short* lBc_ = &lB[buf][0];                              \
        _Pragma("unroll")                                                      \
        for (int ks = 0; ks < 4; ++ks) {                                       \
            const short8 af_ = *(const short8*)(                               \
                lAc_ + m * 64 + (((ks * 2 + q) ^ (m & 7)) * 8));               \
            const short8 bf_ = *(const short8*)(                               \
                lBc_ + (2 * ks + q) * 1024 + (w * 32 + m) * 8);                \
            acc = __builtin_amdgcn_mfma_f32_32x32x16_bf16(af_, bf_, acc, 0, 0, 0); \
        }                                                                      \
    } while (0)

    STAGE(0, 0);
    STAGE(1, 1);

    int rd = 0, wr = 2;
    for (int s = 0; s < 128; ++s) {
        // own step-s loads complete (leaves step-s+1's 5 in flight), then barrier:
        // => ALL waves' step-s LDS writes are done before any wave reads buf rd.
        asm volatile("s_waitcnt vmcnt(5)\n\ts_barrier" ::: "memory");
        STAGE(wr, (s + 2) & 127);   // tail strays write a dead buffer, after barrier: safe
        __builtin_amdgcn_s_setprio(1);
        COMPUTE(rd);
        __builtin_amdgcn_s_setprio(0);
        rd = (rd == 2) ? 0 : rd + 1;
        wr = (wr == 2) ? 0 : wr + 1;
    }

#undef STAGE
#undef COMPUTE

    // epilogue: D row = (reg&3) + 8*(reg>>2) + 4*q, col = lane&31 (HW-verified layout)
#pragma unroll
    for (int g = 0; g < 4; ++g) {
        const ushort4 s4 = *(const ushort4*)(sP + (size_t)(i0 / 8 + g) * (DO * 8)
                                                + (size_t)cc * 8 + 4 * q);
        unsigned short sv[4] = {s4.x, s4.y, s4.z, s4.w};
#pragma unroll
        for (int rr = 0; rr < 4; ++rr) {
            const int row = i0 + 8 * g + 4 * q + rr;
            const float idt = __uint_as_float(((unsigned)sv[rr]) << 16);  // +I contribution
            out[(size_t)row * OUTW + cc] = (acc[g * 4 + rr] + idt) * dinv[row];
        }
    }
}

extern "C" void kernel_launch(void* const* d_in, const int* in_sizes, int n_in,
                              void* d_out, int out_size, void* d_ws, size_t ws_size,
                              hipStream_t stream) {
    (void)in_sizes; (void)n_in; (void)out_size; (void)ws_size;
    const float* in = (const float*)d_in[0];
    const float* w  = (const float*)d_in[1];
    float* out  = (float*)d_out;
    float* d    = (float*)d_ws;                            // 8192 f32 column sums
    float* dinv = d + NSMP;                                // 8192 f32
    unsigned short* sP = (unsigned short*)(d + 2 * NSMP);  // 1024 x 256 x 8 bf16 (4 MB)
    unsigned short* aP = sP + (size_t)1024 * DO * 8;       // 8192 x 8192 bf16 (128 MB)

    hipMemsetAsync(d, 0, NSMP * sizeof(float), stream);
    kcopy<<<dim3(8, 256), 256, 0, stream>>>(in, out, d, aP);
    ksupport<<<1024, 256, 0, stream>>>(in, w, d, dinv, sP);
    kmm<<<512, 256, 0, stream>>>(aP, sP, dinv, out);
}

// Round 5
// 611.634 us; speedup vs baseline: 1.0365x; 1.0365x over previous
//
#include <hip/hip_runtime.h>

#define NSMP 8192
#define INW  8712   // input row stride (floats)
#define OUTW 8448   // output row stride (floats)
#define AOFF 512    // column offset of A block inside input
#define DO   256    // DOUT

typedef __attribute__((ext_vector_type(4)))  float f32x4;
typedef __attribute__((ext_vector_type(8)))  short short8;
typedef __attribute__((ext_vector_type(16))) float floatx16;

typedef __attribute__((address_space(1))) const unsigned int* gptr_t;
typedef __attribute__((address_space(3)))       unsigned int* lptr_t;

// pack two fp32 -> two bf16 (truncation; numerics identical to prior passing versions)
__device__ __forceinline__ unsigned pk_bf16(float lo, float hi) {
    return (__float_as_uint(lo) >> 16) | (__float_as_uint(hi) & 0xffff0000u);
}

// async global->LDS, 16B per lane; LDS dest = wave-uniform base + lane*16
__device__ __forceinline__ void gload_lds16(const void* g, void* l) {
    __builtin_amdgcn_global_load_lds((gptr_t)g, (lptr_t)l, 16, 0, 0);
}

// ------ Kernel A: copy A+I to out[:,256:], col sums -> d, bf16 A -> aP ---------
__global__ __launch_bounds__(256) void kcopy(const float* __restrict__ in,
                                             float* __restrict__ out,
                                             float* __restrict__ d,
                                             unsigned short* __restrict__ aP) {
    const int t  = threadIdx.x;
    const int j0 = blockIdx.x * 1024;   // 8 col tiles of 1024
    const int i0 = blockIdx.y * 32;     // 256 row tiles of 32
    const int jc = j0 + 4 * t;
    const float*    src = in  + (size_t)i0 * INW  + AOFF + jc;
    float*          dst = out + (size_t)i0 * OUTW + DO   + jc;
    unsigned short* ap  = aP  + (size_t)i0 * NSMP + jc;
    f32x4 cs = {0.f, 0.f, 0.f, 0.f};
#pragma unroll 8
    for (int r = 0; r < 32; ++r) {
        f32x4 v = __builtin_nontemporal_load((const f32x4*)(src + (size_t)r * INW));
        uint2 pb;                                     // raw A (no +I) in bf16 for kmm
        pb.x = pk_bf16(v[0], v[1]);
        pb.y = pk_bf16(v[2], v[3]);
        *(uint2*)(ap + (size_t)r * NSMP) = pb;        // normal store: want aP in L3
        int di = (i0 + r) - j0;                       // diagonal col within tile
        if ((di >> 2) == t) {
            int s = di & 3;
            v[0] += (s == 0); v[1] += (s == 1); v[2] += (s == 2); v[3] += (s == 3);
        }
        cs += v;
        __builtin_nontemporal_store(v, (f32x4*)(dst + (size_t)r * OUTW));
    }
    atomicAdd(&d[jc + 0], cs[0]);
    atomicAdd(&d[jc + 1], cs[1]);
    atomicAdd(&d[jc + 2], cs[2]);
    atomicAdd(&d[jc + 3], cs[3]);
}

// ------- Kernel B: support = X@W, write s' packed k-major: sP[oct=k/8][col][k%8] ----
__global__ __launch_bounds__(256) void ksupport(const float* __restrict__ in,
                                                const float* __restrict__ w,
                                                const float* __restrict__ d,
                                                float* __restrict__ dinv,
                                                unsigned short* __restrict__ sP) {
    const int c  = threadIdx.x;          // output column 0..255
    const int r0 = blockIdx.x * 8;       // 8 support-rows per block = one k-octet
    const float* X = in + (size_t)r0 * INW;   // X = input[:, :512]
    float acc[8] = {0.f, 0.f, 0.f, 0.f, 0.f, 0.f, 0.f, 0.f};
#pragma unroll 4
    for (int k = 0; k < 512; ++k) {
        float wv = w[(size_t)k * DO + c];
#pragma unroll
        for (int r = 0; r < 8; ++r)
            acc[r] = fmaf(X[(size_t)r * INW + k], wv, acc[r]);  // X load wave-uniform -> s_load
    }
    union { unsigned short h[8]; uint4 u; } pk;
#pragma unroll
    for (int r = 0; r < 8; ++r) {
        float dv = rsqrtf(d[r0 + r]);
        unsigned ub = __float_as_uint(acc[r] * dv);
        ub += 0x7fffu + ((ub >> 16) & 1u);            // RNE to bf16
        pk.h[r] = (unsigned short)(ub >> 16);
    }
    *(uint4*)(sP + (size_t)(r0 >> 3) * (DO * 8) + (size_t)c * 8) = pk.u;
    if (c < 8) dinv[r0 + c] = rsqrtf(d[r0 + c]);
}

// ---------------- Kernel C: out[:, :256] = dinv_i * (A0 @ s' + s'_i) -----------
// Round-3 data paths + round-4 schedule:
//   A: bf16 gload_lds, 3x4KB XOR-swizzled-source tiles (only LDS user, 12KB total).
//   B: direct global->register (L2-resident sP, contiguous 512B segments), Ba/Bb sets.
// Per step each wave issues exactly 5 VMEM (1 A-stage + 4 B); wait vmcnt(5) then
// s_barrier => the 2-step-old A-tile is complete across ALL waves (5 loads/step are
// queue-contiguous, so "all but last 5 retired" == step s-2 fully retired).
// Stage target (s+2)%3 == (s-1)%3 whose readers all passed this barrier (their
// ds_read data was lgkmcnt-consumed before the MFMAs preceding it). Race-free.
__global__ __launch_bounds__(256, 2) void kmm(const unsigned short* __restrict__ aP,
                                              const unsigned short* __restrict__ sP,
                                              const float* __restrict__ dinv,
                                              float* __restrict__ out) {
    __shared__ __align__(16) unsigned short lA[3][32 * 64];   // 12 KB total

    const int b  = blockIdx.x;
    // XCD-pair swizzle: blocks b and b+8 (same rg, ch=0/1) land on the same XCD (b%8)
    const int rg = ((b >> 4) << 3) + (b & 7);   // 0..255 row group
    const int ch = (b >> 3) & 1;                // column half
    const int tid = threadIdx.x;
    const int w = tid >> 6, lane = tid & 63;
    const int m = lane & 31, q = lane >> 5;
    const int i0 = rg * 32;
    const int cc = ch * 128 + w * 32 + m;

    // A stage: wave w stages rows w*8..w*8+7; lane -> (row = l>>3, slot = l&7);
    // global source pre-swizzled (slot g holds granule g^(row&7)) -> swizzled ds_read
    const int srow = lane >> 3;
    const int sg   = lane & 7;
    const unsigned short* aSrc = aP + (size_t)(i0 + w * 8 + srow) * NSMP
                                    + 8 * (sg ^ (srow & 7));
    const unsigned short* bB   = sP + (size_t)q * 2048 + (size_t)cc * 8;

    floatx16 acc;
#pragma unroll
    for (int z = 0; z < 16; ++z) acc[z] = 0.f;

    uint4 Ba0, Ba1, Ba2, Ba3, Bb0, Bb1, Bb2, Bb3;

#define STAGE_A(nb, s) gload_lds16(aSrc + (size_t)(s) * 64, &lA[nb][w * 512])
#define LOAD_B(P, s) do {                                              \
        P##0 = *(const uint4*)(bB + (size_t)((s) * 8 + 0) * 2048);     \
        P##1 = *(const uint4*)(bB + (size_t)((s) * 8 + 2) * 2048);     \
        P##2 = *(const uint4*)(bB + (size_t)((s) * 8 + 4) * 2048);     \
        P##3 = *(const uint4*)(bB + (size_t)((s) * 8 + 6) * 2048);     \
    } while (0)
#define MFMA_KS(cur, Breg, ks) do {                                    \
        union { uint4 u; short8 s8; } fb_; fb_.u = Breg;               \
        const short8 af_ = *(const short8*)(                           \
            &lA[cur][m * 64 + ((((ks) * 2 + q) ^ (m & 7)) * 8)]);      \
        acc = __builtin_amdgcn_mfma_f32_32x32x16_bf16(af_, fb_.s8, acc, 0, 0, 0); \
    } while (0)
#define COMPUTE(cur, P) do {                                           \
        MFMA_KS(cur, P##0, 0); MFMA_KS(cur, P##1, 1);                  \
        MFMA_KS(cur, P##2, 2); MFMA_KS(cur, P##3, 3);                  \
    } while (0)

    STAGE_A(0, 0);  LOAD_B(Ba, 0);
    STAGE_A(1, 1);  LOAD_B(Bb, 1);

    int rd = 0, wr = 2;
    for (int s = 0; s < 128; s += 2) {
        asm volatile("s_waitcnt vmcnt(5)" ::: "memory");
        __builtin_amdgcn_s_barrier();
        STAGE_A(wr, (s + 2) & 127);          // &127 tail strays hit a dead buffer: safe
        __builtin_amdgcn_s_setprio(1);
        COMPUTE(rd, Ba);                     // WAR on Ba keeps reload below the MFMAs
        __builtin_amdgcn_s_setprio(0);
        LOAD_B(Ba, (s + 2) & 127);
        rd = (rd == 2) ? 0 : rd + 1;
        wr = (wr == 2) ? 0 : wr + 1;

        asm volatile("s_waitcnt vmcnt(5)" ::: "memory");
        __builtin_amdgcn_s_barrier();
        STAGE_A(wr, (s + 3) & 127);
        __builtin_amdgcn_s_setprio(1);
        COMPUTE(rd, Bb);
        __builtin_amdgcn_s_setprio(0);
        LOAD_B(Bb, (s + 3) & 127);
        rd = (rd == 2) ? 0 : rd + 1;
        wr = (wr == 2) ? 0 : wr + 1;
    }

#undef STAGE_A
#undef LOAD_B
#undef MFMA_KS
#undef COMPUTE

    // epilogue: D row = (reg&3) + 8*(reg>>2) + 4*q, col = lane&31 (HW-verified layout)
#pragma unroll
    for (int g = 0; g < 4; ++g) {
        const ushort4 s4 = *(const ushort4*)(sP + (size_t)(i0 / 8 + g) * (DO * 8)
                                                + (size_t)cc * 8 + 4 * q);
        unsigned short sv[4] = {s4.x, s4.y, s4.z, s4.w};
#pragma unroll
        for (int rr = 0; rr < 4; ++rr) {
            const int row = i0 + 8 * g + 4 * q + rr;
            const float idt = __uint_as_float(((unsigned)sv[rr]) << 16);  // +I contribution
            out[(size_t)row * OUTW + cc] = (acc[g * 4 + rr] + idt) * dinv[row];
        }
    }
}

extern "C" void kernel_launch(void* const* d_in, const int* in_sizes, int n_in,
                              void* d_out, int out_size, void* d_ws, size_t ws_size,
                              hipStream_t stream) {
    (void)in_sizes; (void)n_in; (void)out_size; (void)ws_size;
    const float* in = (const float*)d_in[0];
    const float* w  = (const float*)d_in[1];
    float* out  = (float*)d_out;
    float* d    = (float*)d_ws;                            // 8192 f32 column sums
    float* dinv = d + NSMP;                                // 8192 f32
    unsigned short* sP = (unsigned short*)(d + 2 * NSMP);  // 1024 x 256 x 8 bf16 (4 MB)
    unsigned short* aP = sP + (size_t)1024 * DO * 8;       // 8192 x 8192 bf16 (128 MB)

    hipMemsetAsync(d, 0, NSMP * sizeof(float), stream);
    kcopy<<<dim3(8, 256), 256, 0, stream>>>(in, out, d, aP);
    ksupport<<<1024, 256, 0, stream>>>(in, w, d, dinv, sP);
    kmm<<<512, 256, 0, stream>>>(aP, sP, dinv, out);
}